// Round 2
// baseline (243.529 us; speedup 1.0000x reference)
//
#include <hip/hip_runtime.h>
#include <math.h>

#define BB 4
#define CC 64
#define IH 192
#define IW 192
#define OH 384
#define OW 384
#define NE 4
#define NR 4
#define HID 64

__device__ __forceinline__ float gelu_exact(float v) {
    return 0.5f * v * (1.0f + erff(v * 0.70710678118654752f));
}

// ws layout (floats):
//   [0    .. 1023] : wcT[parity][c][r]   (parity = (oy&1)*2 + (ox&1))
//   [1024 .. 2047] : weT[parity][c][r]
//   [2048 .. 2055] : offset[parity][2]   (x, y)
__global__ void precompute_kernel(
    const float* __restrict__ wcomp, const float* __restrict__ wexp,
    const float* __restrict__ bw1, const float* __restrict__ bb1,
    const float* __restrict__ bw2, const float* __restrict__ bb2,
    const float* __restrict__ rw, const float* __restrict__ rb,
    const float* __restrict__ ow, const float* __restrict__ ob,
    float* __restrict__ ws)
{
    __shared__ float s_e1[4][HID];
    __shared__ float s_e2[4][HID];
    __shared__ float s_rt[4][NE];
    const int tid = threadIdx.x;
    const int p = tid >> 6;      // parity 0..3
    const int j = tid & 63;
    // feat = [1/scale_w, 1/scale_h, coor_h, coor_w]; scale = 2 exactly =>
    // coor = -0.25 (even) / +0.25 (odd). p bit1 = oy parity, bit0 = ox parity.
    const float ch = (p & 2) ? 0.25f : -0.25f;
    const float cw = (p & 1) ? 0.25f : -0.25f;
    float a = bw1[j*4+0]*0.5f + bw1[j*4+1]*0.5f + bw1[j*4+2]*ch + bw1[j*4+3]*cw + bb1[j];
    s_e1[p][j] = gelu_exact(a);
    __syncthreads();
    float acc = bb2[j];
    #pragma unroll 8
    for (int k = 0; k < HID; ++k) acc += bw2[j*HID+k]*s_e1[p][k];
    s_e2[p][j] = gelu_exact(acc);
    __syncthreads();
    if (j < NE) {
        float s = rb[j];
        for (int k = 0; k < HID; ++k) s += rw[j*HID+k]*s_e2[p][k];
        s_rt[p][j] = 1.0f/(1.0f+expf(-s));
    } else if (j < NE+2) {
        const int d = j - NE;
        float s = ob[d];
        for (int k = 0; k < HID; ++k) s += ow[d*HID+k]*s_e2[p][k];
        ws[2048 + p*2 + d] = s;
    }
    __syncthreads();
    const int c = j;
    const float r0 = s_rt[p][0], r1 = s_rt[p][1], r2 = s_rt[p][2], r3 = s_rt[p][3];
    #pragma unroll
    for (int r = 0; r < NR; ++r) {
        float v = r0*wcomp[0*NR*CC + r*CC + c] + r1*wcomp[1*NR*CC + r*CC + c]
                + r2*wcomp[2*NR*CC + r*CC + c] + r3*wcomp[3*NR*CC + r*CC + c];
        ws[(p*CC + c)*4 + r] = v;
        float u = r0*wexp[0*CC*NR + c*NR + r] + r1*wexp[1*CC*NR + c*NR + r]
                + r2*wexp[2*CC*NR + c*NR + r] + r3*wexp[3*CC*NR + c*NR + r];
        ws[1024 + (p*CC + c)*4 + r] = u;
    }
}

// block = (64, 4): threadIdx.x = pixel lane (64 consecutive output pixels),
// threadIdx.y = channel group (16 channels each). f[16] per thread keeps
// register pressure low so the gather loop can pipeline.
__global__ __launch_bounds__(256, 4) void upsample_kernel(
    const float* __restrict__ x, const float* __restrict__ ws,
    float* __restrict__ out)
{
    __shared__ __align__(16) float s_tab[2056];
    __shared__ float4 s_mid[4][64];
    const int lane = threadIdx.x;
    const int cg   = threadIdx.y;
    const int tid  = cg*64 + lane;
    for (int i = tid; i < 2056; i += 256) s_tab[i] = ws[i];
    __syncthreads();

    const int pix = blockIdx.x * 64 + lane;
    const int b   = pix / (OH*OW);
    const int rem = pix - b*(OH*OW);
    const int oy  = rem / OW;
    const int ox  = rem - oy*OW;
    const int p   = ((oy & 1) << 1) | (ox & 1);

    const float offx = s_tab[2048 + p*2 + 0];
    const float offy = s_tab[2048 + p*2 + 1];

    const float inv_w1 = 2.0f / 191.0f;   // 2/(w-1), h==w==192
    float gx2 = (((ox + 0.5f)*0.5f - 0.5f) * inv_w1 - 1.0f) + offx * inv_w1;
    float gy2 = (((oy + 0.5f)*0.5f - 0.5f) * inv_w1 - 1.0f) + offy * inv_w1;
    float ix = (gx2 + 1.0f) * 96.0f - 0.5f;   // (g+1)*w/2 - 0.5
    float iy = (gy2 + 1.0f) * 96.0f - 0.5f;

    float x0f = floorf(ix), y0f = floorf(iy);
    float wx1 = ix - x0f, wx0 = 1.0f - wx1;
    float wy1 = iy - y0f, wy0 = 1.0f - wy1;
    float x1f = x0f + 1.0f, y1f = y0f + 1.0f;
    float vx0 = (x0f >= 0.0f && x0f <= 191.0f) ? 1.0f : 0.0f;
    float vx1 = (x1f >= 0.0f && x1f <= 191.0f) ? 1.0f : 0.0f;
    float vy0 = (y0f >= 0.0f && y0f <= 191.0f) ? 1.0f : 0.0f;
    float vy1 = (y1f >= 0.0f && y1f <= 191.0f) ? 1.0f : 0.0f;
    const float w00 = wy0*wx0*vy0*vx0;
    const float w01 = wy0*wx1*vy0*vx1;
    const float w10 = wy1*wx0*vy1*vx0;
    const float w11 = wy1*wx1*vy1*vx1;

    const int xi0 = (int)fminf(fmaxf(x0f, 0.0f), 191.0f);
    const int xi1 = (int)fminf(fmaxf(x1f, 0.0f), 191.0f);
    const int yi0 = (int)fminf(fmaxf(y0f, 0.0f), 191.0f);
    const int yi1 = (int)fminf(fmaxf(y1f, 0.0f), 191.0f);

    const int o00 = yi0*IW + xi0;
    const int o01 = yi0*IW + xi1;
    const int o10 = yi1*IW + xi0;
    const int o11 = yi1*IW + xi1;

    const float* __restrict__ xb = x + b*(CC*IH*IW) + cg*(16*IH*IW);
    const float4* wc4 = ((const float4*)s_tab) + p*CC + cg*16;        // wcT
    const float4* we4 = ((const float4*)s_tab) + 256 + p*CC + cg*16;  // weT

    float f[16];
    float4 mid = make_float4(0.f, 0.f, 0.f, 0.f);
    #pragma unroll
    for (int j = 0; j < 16; ++j) {
        const int o = j*(IH*IW);
        float v = w00*xb[o+o00] + w01*xb[o+o01] + w10*xb[o+o10] + w11*xb[o+o11];
        f[j] = v;
        float4 wc = wc4[j];
        mid.x += wc.x*v; mid.y += wc.y*v; mid.z += wc.z*v; mid.w += wc.w*v;
    }
    s_mid[cg][lane] = mid;
    __syncthreads();
    float4 m0 = s_mid[0][lane], m1 = s_mid[1][lane],
           m2 = s_mid[2][lane], m3 = s_mid[3][lane];
    const float mid0 = m0.x + m1.x + m2.x + m3.x;
    const float mid1 = m0.y + m1.y + m2.y + m3.y;
    const float mid2 = m0.z + m1.z + m2.z + m3.z;
    const float mid3 = m0.w + m1.w + m2.w + m3.w;

    float* __restrict__ op = out + b*(CC*OH*OW) + cg*(16*OH*OW) + oy*OW + ox;
    #pragma unroll
    for (int j = 0; j < 16; ++j) {
        float4 we = we4[j];
        float v = f[j] + we.x*mid0 + we.y*mid1 + we.z*mid2 + we.w*mid3;
        __builtin_nontemporal_store(v, op + j*(OH*OW));
    }
}

extern "C" void kernel_launch(void* const* d_in, const int* in_sizes, int n_in,
                              void* d_out, int out_size, void* d_ws, size_t ws_size,
                              hipStream_t stream) {
    const float* x     = (const float*)d_in[0];
    const float* wcomp = (const float*)d_in[1];
    const float* wexp  = (const float*)d_in[2];
    const float* bw1   = (const float*)d_in[3];
    const float* bb1   = (const float*)d_in[4];
    const float* bw2   = (const float*)d_in[5];
    const float* bb2   = (const float*)d_in[6];
    const float* rw    = (const float*)d_in[7];
    const float* rb    = (const float*)d_in[8];
    const float* ow    = (const float*)d_in[9];
    const float* ob    = (const float*)d_in[10];
    float* ws  = (float*)d_ws;
    float* out = (float*)d_out;

    precompute_kernel<<<1, 256, 0, stream>>>(wcomp, wexp, bw1, bb1, bw2, bb2,
                                             rw, rb, ow, ob, ws);
    const int total_pix = BB*OH*OW;                  // 589824 = 9216 * 64
    dim3 block(64, 4);
    upsample_kernel<<<total_pix/64, block, 0, stream>>>(x, ws, out);
}

// Round 3
// 236.838 us; speedup vs baseline: 1.0282x; 1.0282x over previous
//
#include <hip/hip_runtime.h>
#include <math.h>

#define BB 4
#define CC 64
#define IH 192
#define IW 192
#define OH 384
#define OW 384
#define NE 4
#define NR 4
#define HID 64

__device__ __forceinline__ float gelu_exact(float v) {
    return 0.5f * v * (1.0f + erff(v * 0.70710678118654752f));
}

// ws layout (floats):
//   [0    .. 1023] : wcT[parity][c][r]   (parity = (oy&1)*2 + (ox&1))
//   [1024 .. 2047] : weT[parity][c][r]
//   [2048 .. 2055] : offset[parity][2]   (x, y)
__global__ void precompute_kernel(
    const float* __restrict__ wcomp, const float* __restrict__ wexp,
    const float* __restrict__ bw1, const float* __restrict__ bb1,
    const float* __restrict__ bw2, const float* __restrict__ bb2,
    const float* __restrict__ rw, const float* __restrict__ rb,
    const float* __restrict__ ow, const float* __restrict__ ob,
    float* __restrict__ ws)
{
    __shared__ float s_e1[4][HID];
    __shared__ float s_e2[4][HID];
    __shared__ float s_rt[4][NE];
    const int tid = threadIdx.x;
    const int p = tid >> 6;      // parity 0..3
    const int j = tid & 63;
    // scale = 2 exactly => coor = -0.25 (even) / +0.25 (odd).
    const float ch = (p & 2) ? 0.25f : -0.25f;
    const float cw = (p & 1) ? 0.25f : -0.25f;
    float a = bw1[j*4+0]*0.5f + bw1[j*4+1]*0.5f + bw1[j*4+2]*ch + bw1[j*4+3]*cw + bb1[j];
    s_e1[p][j] = gelu_exact(a);
    __syncthreads();
    float acc = bb2[j];
    #pragma unroll 8
    for (int k = 0; k < HID; ++k) acc += bw2[j*HID+k]*s_e1[p][k];
    s_e2[p][j] = gelu_exact(acc);
    __syncthreads();
    if (j < NE) {
        float s = rb[j];
        for (int k = 0; k < HID; ++k) s += rw[j*HID+k]*s_e2[p][k];
        s_rt[p][j] = 1.0f/(1.0f+expf(-s));
    } else if (j < NE+2) {
        const int d = j - NE;
        float s = ob[d];
        for (int k = 0; k < HID; ++k) s += ow[d*HID+k]*s_e2[p][k];
        ws[2048 + p*2 + d] = s;
    }
    __syncthreads();
    const int c = j;
    const float r0 = s_rt[p][0], r1 = s_rt[p][1], r2 = s_rt[p][2], r3 = s_rt[p][3];
    #pragma unroll
    for (int r = 0; r < NR; ++r) {
        float v = r0*wcomp[0*NR*CC + r*CC + c] + r1*wcomp[1*NR*CC + r*CC + c]
                + r2*wcomp[2*NR*CC + r*CC + c] + r3*wcomp[3*NR*CC + r*CC + c];
        ws[(p*CC + c)*4 + r] = v;
        float u = r0*wexp[0*CC*NR + c*NR + r] + r1*wexp[1*CC*NR + c*NR + r]
                + r2*wexp[2*CC*NR + c*NR + r] + r3*wexp[3*CC*NR + c*NR + r];
        ws[1024 + (p*CC + c)*4 + r] = u;
    }
}

// block (64,4): lane = output x within a 64-wide strip (parity-swizzled:
// lanes 0-31 even ox, 32-63 odd ox so each half-wave's gathers are stride-1),
// threadIdx.y = channel group (16 ch). Each thread computes TWO output rows
// (oy, oy+2) — same parity, same wy fractions, y-corners differ by exactly 1
// input row => 3 input rows x 2 cols = 6 gathers/channel for 2 pixels.
__global__ __launch_bounds__(256) void upsample_kernel(
    const float* __restrict__ x, const float* __restrict__ ws,
    float* __restrict__ out)
{
    __shared__ __align__(16) float s_tab[2056];
    __shared__ float4 s_mid[4][2][64];
    const int lane = threadIdx.x;
    const int cg   = threadIdx.y;
    const int tid  = cg*64 + lane;
    for (int i = tid; i < 2056; i += 256) s_tab[i] = ws[i];
    __syncthreads();

    const int half = lane >> 5;           // ox parity
    const int i32  = lane & 31;
    const int ox   = blockIdx.x*64 + 2*i32 + half;
    const int rp   = blockIdx.y;          // row-pair index [0,192)
    const int oy_a = ((rp >> 1) << 2) + (rp & 1);   // {0,1,4,5,8,...}
    const int oy_b = oy_a + 2;
    const int b    = blockIdx.z;
    const int p    = ((rp & 1) << 1) | half;        // parity class

    const float offx = s_tab[2048 + p*2 + 0];
    const float offy = s_tab[2048 + p*2 + 1];

    const float k191 = 192.0f / 191.0f;
    float ix = (((ox + 0.5f)*0.5f - 0.5f) + offx) * k191 - 0.5f;
    float iy = (((oy_a + 0.5f)*0.5f - 0.5f) + offy) * k191 - 0.5f;

    float x0f = floorf(ix);
    float wx1f = ix - x0f, wx0f = 1.0f - wx1f;
    float x1f = x0f + 1.0f;
    float vx0 = (x0f >= 0.0f && x0f <= 191.0f) ? 1.0f : 0.0f;
    float vx1 = (x1f >= 0.0f && x1f <= 191.0f) ? 1.0f : 0.0f;
    const float wx0 = wx0f * vx0;
    const float wx1 = wx1f * vx1;
    const int xi0 = (int)fminf(fmaxf(x0f, 0.0f), 191.0f);
    const int xi1 = (int)fminf(fmaxf(x1f, 0.0f), 191.0f);

    float y0f = floorf(iy);
    float wy1f = iy - y0f, wy0f = 1.0f - wy1f;
    // rows y0, y0+1, y0+2 (pixel a uses rows 0,1; pixel b rows 1,2)
    float r0f = y0f, r1f = y0f + 1.0f, r2f = y0f + 2.0f;
    float v0 = (r0f >= 0.0f && r0f <= 191.0f) ? 1.0f : 0.0f;
    float v1 = (r1f >= 0.0f && r1f <= 191.0f) ? 1.0f : 0.0f;
    float v2 = (r2f >= 0.0f && r2f <= 191.0f) ? 1.0f : 0.0f;
    const float wya0 = wy0f * v0, wya1 = wy1f * v1;
    const float wyb0 = wy0f * v1, wyb1 = wy1f * v2;
    const int yi0 = (int)fminf(fmaxf(r0f, 0.0f), 191.0f);
    const int yi1 = (int)fminf(fmaxf(r1f, 0.0f), 191.0f);
    const int yi2 = (int)fminf(fmaxf(r2f, 0.0f), 191.0f);

    const int o00 = yi0*IW + xi0, o01 = yi0*IW + xi1;
    const int o10 = yi1*IW + xi0, o11 = yi1*IW + xi1;
    const int o20 = yi2*IW + xi0, o21 = yi2*IW + xi1;

    const float* __restrict__ xb = x + b*(CC*IH*IW) + cg*(16*IH*IW);
    const float4* wc4 = ((const float4*)s_tab) + p*CC + cg*16;        // wcT
    const float4* we4 = ((const float4*)s_tab) + 256 + p*CC + cg*16;  // weT

    float fa[16], fb[16];
    float4 mida = make_float4(0.f,0.f,0.f,0.f);
    float4 midb = make_float4(0.f,0.f,0.f,0.f);
    #pragma unroll
    for (int j = 0; j < 16; ++j) {
        const float* __restrict__ bp = xb + j*(IH*IW);
        float a00 = bp[o00], a01 = bp[o01];
        float a10 = bp[o10], a11 = bp[o11];
        float a20 = bp[o20], a21 = bp[o21];
        float rd0 = wx0*a00 + wx1*a01;
        float rd1 = wx0*a10 + wx1*a11;
        float rd2 = wx0*a20 + wx1*a21;
        float va = wya0*rd0 + wya1*rd1;
        float vb = wyb0*rd1 + wyb1*rd2;
        fa[j] = va; fb[j] = vb;
        float4 wc = wc4[j];
        mida.x += wc.x*va; mida.y += wc.y*va; mida.z += wc.z*va; mida.w += wc.w*va;
        midb.x += wc.x*vb; midb.y += wc.y*vb; midb.z += wc.z*vb; midb.w += wc.w*vb;
    }
    s_mid[cg][0][lane] = mida;
    s_mid[cg][1][lane] = midb;
    __syncthreads();
    float4 a0 = s_mid[0][0][lane], a1 = s_mid[1][0][lane],
           a2 = s_mid[2][0][lane], a3 = s_mid[3][0][lane];
    float4 b0 = s_mid[0][1][lane], b1 = s_mid[1][1][lane],
           b2 = s_mid[2][1][lane], b3 = s_mid[3][1][lane];
    const float ma0 = a0.x+a1.x+a2.x+a3.x, ma1 = a0.y+a1.y+a2.y+a3.y;
    const float ma2 = a0.z+a1.z+a2.z+a3.z, ma3 = a0.w+a1.w+a2.w+a3.w;
    const float mb0 = b0.x+b1.x+b2.x+b3.x, mb1 = b0.y+b1.y+b2.y+b3.y;
    const float mb2 = b0.z+b1.z+b2.z+b3.z, mb3 = b0.w+b1.w+b2.w+b3.w;

    float* __restrict__ opa = out + b*(CC*OH*OW) + cg*(16*OH*OW) + oy_a*OW + ox;
    float* __restrict__ opb = opa + 2*OW;
    #pragma unroll
    for (int j = 0; j < 16; ++j) {
        float4 we = we4[j];
        opa[j*(OH*OW)] = fa[j] + we.x*ma0 + we.y*ma1 + we.z*ma2 + we.w*ma3;
        opb[j*(OH*OW)] = fb[j] + we.x*mb0 + we.y*mb1 + we.z*mb2 + we.w*mb3;
    }
}

extern "C" void kernel_launch(void* const* d_in, const int* in_sizes, int n_in,
                              void* d_out, int out_size, void* d_ws, size_t ws_size,
                              hipStream_t stream) {
    const float* x     = (const float*)d_in[0];
    const float* wcomp = (const float*)d_in[1];
    const float* wexp  = (const float*)d_in[2];
    const float* bw1   = (const float*)d_in[3];
    const float* bb1   = (const float*)d_in[4];
    const float* bw2   = (const float*)d_in[5];
    const float* bb2   = (const float*)d_in[6];
    const float* rw    = (const float*)d_in[7];
    const float* rb    = (const float*)d_in[8];
    const float* ow    = (const float*)d_in[9];
    const float* ob    = (const float*)d_in[10];
    float* ws  = (float*)d_ws;
    float* out = (float*)d_out;

    precompute_kernel<<<1, 256, 0, stream>>>(wcomp, wexp, bw1, bb1, bw2, bb2,
                                             rw, rb, ow, ob, ws);
    dim3 block(64, 4);
    dim3 grid(OW/64, OH/2, BB);   // 6 x 192 x 4 = 4608 blocks
    upsample_kernel<<<grid, block, 0, stream>>>(x, ws, out);
}